// Round 17
// baseline (86.965 us; speedup 1.0000x reference)
//
#include <hip/hip_runtime.h>

#define EPSI 1e-5f

typedef __attribute__((ext_vector_type(8))) short bf16x8;
typedef __attribute__((ext_vector_type(4))) float f32x4;

__device__ __forceinline__ float lrelu(float x) { return x > 0.f ? x : 0.01f * x; }

// float -> bf16 bits, round-to-nearest-even (header-free)
__device__ __forceinline__ unsigned short f2bf(float x) {
    unsigned int u = __float_as_uint(x);
    return (unsigned short)((u + 0x7fffu + ((u >> 16) & 1u)) >> 16);
}
__device__ __forceinline__ float bflo(unsigned int v) { return __uint_as_float(v << 16); }
__device__ __forceinline__ float bfhi(unsigned int v) { return __uint_as_float(v & 0xFFFF0000u); }
__device__ __forceinline__ unsigned int pack2(float a, float b) {
    return (unsigned int)f2bf(a) | ((unsigned int)f2bf(b) << 16);
}
__device__ __forceinline__ bf16x8 pack8(float4 a, float4 b) {
    union { unsigned short u[8]; bf16x8 v; } p;
    p.u[0] = f2bf(a.x); p.u[1] = f2bf(a.y); p.u[2] = f2bf(a.z); p.u[3] = f2bf(a.w);
    p.u[4] = f2bf(b.x); p.u[5] = f2bf(b.y); p.u[6] = f2bf(b.z); p.u[7] = f2bf(b.w);
    return p.v;
}

// Block-wide sum of (a,b). blockDim.x == 256.
__device__ __forceinline__ float2 block_reduce_sum2(float a, float b) {
    #pragma unroll
    for (int off = 1; off < 64; off <<= 1) {
        a += __shfl_xor(a, off, 64);
        b += __shfl_xor(b, off, 64);
    }
    __shared__ float lds[8];
    const int t = threadIdx.x;
    if ((t & 63) == 0) { lds[2 * (t >> 6)] = a; lds[2 * (t >> 6) + 1] = b; }
    __syncthreads();
    a = lds[0] + lds[2] + lds[4] + lds[6];
    b = lds[1] + lds[3] + lds[5] + lds[7];
    return make_float2(a, b);
}

// Packed activation layouts (bf16), all in LDS inside k1234:
//   h1s [4icq][64y][64x][4c] = 128KB;  h2s [8icq][32y][32x][4c] = 64KB (aliases h1s);
//   h3s [16icq][16y][16x][4c] = 32KB;  psA/psB = 2x32KB (alias dead h2s in phase C).
// h4 global standard [n][128co][64px] (feeds FC1 GEMM).
// Conv GEMM k-order: k = icq*16 + row*8 + tx*4 + c  -> one 16B load per lane K-octet.
// wk: wk2 at 0 (32x64), wk3 at 2048 (64x128), wk4 at 10240 (128x256).

// ---------------- WPREP: reorder conv weights to bf16 wk[co][k] ------------------
__global__ __launch_bounds__(1024) void wprep(const float* __restrict__ w2,
                                              const float* __restrict__ w3,
                                              const float* __restrict__ w4,
                                              unsigned short* __restrict__ wk) {
    const int g = blockIdx.x * 1024 + threadIdx.x;
    if (g < 2048) {
        const int co = g >> 6, k = g & 63;
        const int ic = (k >> 4) * 4 + (k & 3), row = (k >> 3) & 1, tx = (k >> 2) & 1;
        wk[g] = f2bf(w2[co * 144 + ic * 4 + row * 2 + tx]);
    } else if (g < 10240) {
        const int e = g - 2048, co = e >> 7, k = e & 127;
        const int ic = (k >> 4) * 4 + (k & 3), row = (k >> 3) & 1, tx = (k >> 2) & 1;
        wk[g] = f2bf(w3[co * 128 + ic * 4 + row * 2 + tx]);
    } else if (g < 43008) {
        const int e = g - 10240, co = e >> 8, k = e & 255;
        const int ic = (k >> 4) * 4 + (k & 3), row = (k >> 3) & 1, tx = (k >> 2) & 1;
        wk[g] = f2bf(w4[co * 256 + ic * 4 + row * 2 + tx]);
    }
}

// ---------------- K1234: conv1..conv4 fully fused, per-sample --------------------
// 1024 thr (16 waves), 1 block/CU (LDS-bound). R16 counters: VGPR=52 => compiler
// loop-distributed phase 0 (acc>cap); phase C used 8/16 waves. Fixed here:
// phase 0 = explicit 2 co-octet passes (acc[8][4]=32 live, float4 x loads, uint4
// stores); phase C = 4-way K split across all 16 waves with 2-stage LDS combine.
__global__ __launch_bounds__(1024, 1) void k1234(const float* __restrict__ x,
                                                 const float* __restrict__ w1,
                                                 const unsigned short* __restrict__ wk,
                                                 unsigned short* __restrict__ h4) {
    const int n = blockIdx.x;
    const int t = threadIdx.x;
    const int w = t >> 6, l = t & 63;
    __shared__ __align__(16) unsigned char smem[131072];   // 128KB phase-aliased
    __shared__ float red[16][64][2];                       // 8KB
    __shared__ float msc[64][2];
    unsigned short* h1s = (unsigned short*)smem;           // [0,128K) phase 0 -> A
    unsigned short* h2s = (unsigned short*)smem;           // [0,64K)  phase A -> B
    unsigned short* h3s = (unsigned short*)(smem + 65536); // [64K,96K) phase B -> C
    float* psA = (float*)smem;                             // [0,32K)  phase C combine
    float* psB = (float*)(smem + 32768);                   // [32K,64K)

    // ======== Phase 0: conv1 (VALU, 2 co-octet passes) + IN + lrelu -> h1s =======
    // Thread owns px pairs (2p, 2p+1), p = t + 1024*qq: x patch rows = one float4.
    {
        const float* xn = x + (size_t)n * 49152;
        #pragma unroll 1
        for (int pass = 0; pass < 2; ++pass) {
            float acc[8][4];   // [co_local][qq*2+sub]
            #pragma unroll
            for (int j = 0; j < 8; ++j)
                #pragma unroll
                for (int q = 0; q < 4; ++q) acc[j][q] = 0.f;
            float4 r0[2][3], r1[2][3];   // [qq][ic]
            #pragma unroll
            for (int qq = 0; qq < 2; ++qq) {
                const int p = t + 1024 * qq;
                const int oy = p >> 5;
                const int ox0 = (2 * p) & 63;
                #pragma unroll
                for (int ic = 0; ic < 3; ++ic) {
                    r0[qq][ic] = *(const float4*)(xn + ic * 16384 + (2 * oy) * 128 + 2 * ox0);
                    r1[qq][ic] = *(const float4*)(xn + ic * 16384 + (2 * oy + 1) * 128 + 2 * ox0);
                }
            }
            #pragma unroll
            for (int j = 0; j < 8; ++j) {
                #pragma unroll
                for (int ic = 0; ic < 3; ++ic) {
                    const float4 wv = *(const float4*)(w1 + (pass * 8 + j) * 12 + ic * 4);  // SGPR
                    #pragma unroll
                    for (int qq = 0; qq < 2; ++qq) {
                        acc[j][qq * 2 + 0] += r0[qq][ic].x * wv.x + r0[qq][ic].y * wv.y +
                                              r1[qq][ic].x * wv.z + r1[qq][ic].y * wv.w;
                        acc[j][qq * 2 + 1] += r0[qq][ic].z * wv.x + r0[qq][ic].w * wv.y +
                                              r1[qq][ic].z * wv.z + r1[qq][ic].w * wv.w;
                    }
                }
            }
            #pragma unroll
            for (int j = 0; j < 8; ++j) {
                float s1 = acc[j][0] + acc[j][1] + acc[j][2] + acc[j][3];
                float s2 = acc[j][0] * acc[j][0] + acc[j][1] * acc[j][1] +
                           acc[j][2] * acc[j][2] + acc[j][3] * acc[j][3];
                #pragma unroll
                for (int off = 1; off < 64; off <<= 1) {
                    s1 += __shfl_xor(s1, off, 64);
                    s2 += __shfl_xor(s2, off, 64);
                }
                if (l == 0) { red[w][j][0] = s1; red[w][j][1] = s2; }
            }
            __syncthreads();
            if (t < 8) {
                float s1 = 0.f, s2 = 0.f;
                #pragma unroll
                for (int ww = 0; ww < 16; ++ww) { s1 += red[ww][t][0]; s2 += red[ww][t][1]; }
                const float mean = s1 * (1.f / 4096.f);
                const float var = s2 * (1.f / 4096.f) - mean * mean;
                msc[t][0] = mean; msc[t][1] = rsqrtf(var + EPSI);
            }
            __syncthreads();
            #pragma unroll
            for (int qq = 0; qq < 2; ++qq) {
                const int p = t + 1024 * qq;
                const int oy = p >> 5;
                const int ox0 = (2 * p) & 63;
                const int base = (oy * 64 + ox0) * 4;   // elem offset in icq plane
                #pragma unroll
                for (int c4 = 0; c4 < 2; ++c4) {
                    const int icq = pass * 2 + c4;
                    float ns[2][4];
                    #pragma unroll
                    for (int s = 0; s < 2; ++s)
                        #pragma unroll
                        for (int c = 0; c < 4; ++c)
                            ns[s][c] = lrelu((acc[c4 * 4 + c][qq * 2 + s] - msc[c4 * 4 + c][0]) *
                                             msc[c4 * 4 + c][1]);
                    uint4 u;
                    u.x = pack2(ns[0][0], ns[0][1]); u.y = pack2(ns[0][2], ns[0][3]);
                    u.z = pack2(ns[1][0], ns[1][1]); u.w = pack2(ns[1][2], ns[1][3]);
                    *(uint4*)(&h1s[icq * 16384 + base]) = u;
                }
            }
            __syncthreads();   // red/msc reuse; after pass 2 = phase A readiness
        }
    }

    // ======== Phase A: conv2 [32co x 64K x 1024px], h1s -> h2s ========
    {
        const unsigned short* wk2 = wk;
        bf16x8 af[2][2];
        #pragma unroll
        for (int cf = 0; cf < 2; ++cf)
            #pragma unroll
            for (int ks = 0; ks < 2; ++ks)
                af[cf][ks] = *(const bf16x8*)(wk2 + (cf * 16 + (l & 15)) * 64 + ks * 32 + (l >> 4) * 8);
        f32x4 acc[4][2];
        const f32x4 z = {0.f, 0.f, 0.f, 0.f};
        #pragma unroll
        for (int pg = 0; pg < 4; ++pg) { acc[pg][0] = z; acc[pg][1] = z; }
        const int row = (l >> 4) & 1, icq0 = (l >> 4) >> 1;
        #pragma unroll
        for (int pg = 0; pg < 4; ++pg) {
            const int oy = 2 * w + (pg >> 1);
            const int ox = (pg & 1) * 16 + (l & 15);
            #pragma unroll
            for (int ks = 0; ks < 2; ++ks) {
                const bf16x8 bv = *(const bf16x8*)(&h1s[(ks * 2 + icq0) * 16384 + (2 * oy + row) * 256 + ox * 8]);
                acc[pg][0] = __builtin_amdgcn_mfma_f32_16x16x32_bf16(af[0][ks], bv, acc[pg][0], 0, 0, 0);
                acc[pg][1] = __builtin_amdgcn_mfma_f32_16x16x32_bf16(af[1][ks], bv, acc[pg][1], 0, 0, 0);
            }
        }
        #pragma unroll
        for (int cf = 0; cf < 2; ++cf) {
            #pragma unroll
            for (int r = 0; r < 4; ++r) {
                float s1 = acc[0][cf][r] + acc[1][cf][r] + acc[2][cf][r] + acc[3][cf][r];
                float s2 = acc[0][cf][r] * acc[0][cf][r] + acc[1][cf][r] * acc[1][cf][r] +
                           acc[2][cf][r] * acc[2][cf][r] + acc[3][cf][r] * acc[3][cf][r];
                #pragma unroll
                for (int off = 1; off < 16; off <<= 1) {
                    s1 += __shfl_xor(s1, off, 64);
                    s2 += __shfl_xor(s2, off, 64);
                }
                if ((l & 15) == 0) {
                    red[w][cf * 16 + (l >> 4) * 4 + r][0] = s1;
                    red[w][cf * 16 + (l >> 4) * 4 + r][1] = s2;
                }
            }
        }
        __syncthreads();   // all h1s reads complete -> h2s may alias h1s
        if (t < 32) {
            float s1 = 0.f, s2 = 0.f;
            #pragma unroll
            for (int ww = 0; ww < 16; ++ww) { s1 += red[ww][t][0]; s2 += red[ww][t][1]; }
            const float mean = s1 * (1.f / 1024.f);
            const float var = s2 * (1.f / 1024.f) - mean * mean;
            msc[t][0] = mean; msc[t][1] = rsqrtf(var + EPSI);
        }
        __syncthreads();
        #pragma unroll
        for (int pg = 0; pg < 4; ++pg) {
            const int px = w * 64 + pg * 16 + (l & 15);
            #pragma unroll
            for (int cf = 0; cf < 2; ++cf) {
                const int co0 = cf * 16 + (l >> 4) * 4;
                float v[4];
                #pragma unroll
                for (int r = 0; r < 4; ++r)
                    v[r] = lrelu((acc[pg][cf][r] - msc[co0 + r][0]) * msc[co0 + r][1]);
                uint2 u; u.x = pack2(v[0], v[1]); u.y = pack2(v[2], v[3]);
                *(uint2*)(&h2s[((cf * 4 + (l >> 4)) * 1024 + px) * 4]) = u;
            }
        }
    }
    __syncthreads();

    // ======== Phase B: conv3 [64co x 128K x 256px], h2s -> h3s ========
    {
        const unsigned short* wk3 = wk + 2048;
        f32x4 acc[4];
        const f32x4 z = {0.f, 0.f, 0.f, 0.f};
        #pragma unroll
        for (int cf = 0; cf < 4; ++cf) acc[cf] = z;
        const int row = (l >> 4) & 1, icq0 = (l >> 4) >> 1;
        #pragma unroll
        for (int ks = 0; ks < 4; ++ks) {
            const bf16x8 bv = *(const bf16x8*)(&h2s[(ks * 2 + icq0) * 4096 + (2 * w + row) * 128 + (l & 15) * 8]);
            #pragma unroll
            for (int cf = 0; cf < 4; ++cf) {
                const bf16x8 af = *(const bf16x8*)(wk3 + (cf * 16 + (l & 15)) * 128 + ks * 32 + (l >> 4) * 8);
                acc[cf] = __builtin_amdgcn_mfma_f32_16x16x32_bf16(af, bv, acc[cf], 0, 0, 0);
            }
        }
        #pragma unroll
        for (int cf = 0; cf < 4; ++cf) {
            #pragma unroll
            for (int r = 0; r < 4; ++r) {
                float s1 = acc[cf][r], s2 = acc[cf][r] * acc[cf][r];
                #pragma unroll
                for (int off = 1; off < 16; off <<= 1) {
                    s1 += __shfl_xor(s1, off, 64);
                    s2 += __shfl_xor(s2, off, 64);
                }
                if ((l & 15) == 0) {
                    red[w][cf * 16 + (l >> 4) * 4 + r][0] = s1;
                    red[w][cf * 16 + (l >> 4) * 4 + r][1] = s2;
                }
            }
        }
        __syncthreads();
        if (t < 64) {
            float s1 = 0.f, s2 = 0.f;
            #pragma unroll
            for (int ww = 0; ww < 16; ++ww) { s1 += red[ww][t][0]; s2 += red[ww][t][1]; }
            const float mean = s1 * (1.f / 256.f);
            const float var = s2 * (1.f / 256.f) - mean * mean;
            msc[t][0] = mean; msc[t][1] = rsqrtf(var + EPSI);
        }
        __syncthreads();
        const int px = w * 16 + (l & 15);
        #pragma unroll
        for (int cf = 0; cf < 4; ++cf) {
            const int co0 = cf * 16 + (l >> 4) * 4;
            float v[4];
            #pragma unroll
            for (int r = 0; r < 4; ++r)
                v[r] = lrelu((acc[cf][r] - msc[co0 + r][0]) * msc[co0 + r][1]);
            uint2 u; u.x = pack2(v[0], v[1]); u.y = pack2(v[2], v[3]);
            *(uint2*)(&h3s[((cf * 4 + (l >> 4)) * 256 + px) * 4]) = u;
        }
    }
    __syncthreads();

    // ======== Phase C: conv4 [128co x 256K x 64px], h3s -> h4, ALL 16 waves ======
    // wave = (kq = w>>2: K quarter, cfp = w&3: co pair). 2-stage combine in psA/psB
    // (alias dead h2s region); kq0 waves finish IN + store.
    {
        const unsigned short* wk4 = wk + 10240;
        const int cfp = w & 3, kq = w >> 2;
        f32x4 acc[4][2];
        const f32x4 z = {0.f, 0.f, 0.f, 0.f};
        #pragma unroll
        for (int pg = 0; pg < 4; ++pg) { acc[pg][0] = z; acc[pg][1] = z; }
        const int row = (l >> 4) & 1, icq0 = (l >> 4) >> 1;
        const int oyb = (l & 15) >> 3, ox = l & 7;
        #pragma unroll
        for (int ksl = 0; ksl < 2; ++ksl) {
            const int ks = kq * 2 + ksl;
            bf16x8 af0 = *(const bf16x8*)(wk4 + ((cfp * 2 + 0) * 16 + (l & 15)) * 256 + ks * 32 + (l >> 4) * 8);
            bf16x8 af1 = *(const bf16x8*)(wk4 + ((cfp * 2 + 1) * 16 + (l & 15)) * 256 + ks * 32 + (l >> 4) * 8);
            #pragma unroll
            for (int pg = 0; pg < 4; ++pg) {
                const int oy = pg * 2 + oyb;
                const bf16x8 bv = *(const bf16x8*)(&h3s[(ks * 2 + icq0) * 1024 + (2 * oy + row) * 64 + ox * 8]);
                acc[pg][0] = __builtin_amdgcn_mfma_f32_16x16x32_bf16(af0, bv, acc[pg][0], 0, 0, 0);
                acc[pg][1] = __builtin_amdgcn_mfma_f32_16x16x32_bf16(af1, bv, acc[pg][1], 0, 0, 0);
            }
        }
        const int pbase = (cfp * 64 + l) * 32;
        if (kq == 1 || kq == 3) {
            float* dst = (kq == 1) ? psA : psB;
            #pragma unroll
            for (int pg = 0; pg < 4; ++pg)
                #pragma unroll
                for (int cfi = 0; cfi < 2; ++cfi)
                    #pragma unroll
                    for (int r = 0; r < 4; ++r)
                        dst[pbase + pg * 8 + cfi * 4 + r] = acc[pg][cfi][r];
        }
        __syncthreads();
        if (kq == 0) {
            #pragma unroll
            for (int pg = 0; pg < 4; ++pg)
                #pragma unroll
                for (int cfi = 0; cfi < 2; ++cfi)
                    #pragma unroll
                    for (int r = 0; r < 4; ++r)
                        acc[pg][cfi][r] += psA[pbase + pg * 8 + cfi * 4 + r];
        } else if (kq == 2) {
            #pragma unroll
            for (int pg = 0; pg < 4; ++pg)
                #pragma unroll
                for (int cfi = 0; cfi < 2; ++cfi)
                    #pragma unroll
                    for (int r = 0; r < 4; ++r) {
                        acc[pg][cfi][r] += psB[pbase + pg * 8 + cfi * 4 + r];
                        psB[pbase + pg * 8 + cfi * 4 + r] = acc[pg][cfi][r];
                    }
        }
        __syncthreads();
        if (kq == 0) {
            unsigned short* on = h4 + (size_t)n * 8192;
            #pragma unroll
            for (int cfi = 0; cfi < 2; ++cfi) {
                #pragma unroll
                for (int r = 0; r < 4; ++r) {
                    float v[4];
                    #pragma unroll
                    for (int pg = 0; pg < 4; ++pg)
                        v[pg] = acc[pg][cfi][r] + psB[pbase + pg * 8 + cfi * 4 + r];
                    float s1 = v[0] + v[1] + v[2] + v[3];
                    float s2 = v[0] * v[0] + v[1] * v[1] + v[2] * v[2] + v[3] * v[3];
                    #pragma unroll
                    for (int off = 1; off < 16; off <<= 1) {
                        s1 += __shfl_xor(s1, off, 64);
                        s2 += __shfl_xor(s2, off, 64);
                    }
                    const float mean = s1 * (1.f / 64.f);
                    const float var = s2 * (1.f / 64.f) - mean * mean;
                    const float sc = rsqrtf(var + EPSI);
                    const int co = (cfp * 2 + cfi) * 16 + (l >> 4) * 4 + r;
                    #pragma unroll
                    for (int pg = 0; pg < 4; ++pg)
                        on[co * 64 + pg * 16 + (l & 15)] = f2bf(lrelu((v[pg] - mean) * sc));
                }
            }
        }
    }
}

// ---------------- K5: FC1 bf16 MFMA split-K GEMM, SK=32, bf16 partials -----------
__global__ __launch_bounds__(256, 2) void k5_fc1(const unsigned short* __restrict__ A,
                                                 const float* __restrict__ Wf,
                                                 unsigned short* __restrict__ Cp) {
    __shared__ unsigned short As[128 * 72];
    __shared__ unsigned short Bs[128 * 72];
    const int t = threadIdx.x;
    const int sk = blockIdx.x >> 4;          // 0..31
    const int tile = blockIdx.x & 15;
    const int mt = tile >> 3, nt = tile & 7;
    const int m0 = mt * 128, n0 = nt * 128;
    const int w = t >> 6, l = t & 63;
    const int wm = (w >> 1) * 64, wn = (w & 1) * 64;
    const int lr16 = l & 15, lk8 = (l >> 4) * 8;
    const int srow = t >> 3, scol = (t & 7) * 8;
    f32x4 acc[4][4];
    const f32x4 z = {0.f, 0.f, 0.f, 0.f};
    #pragma unroll
    for (int f = 0; f < 4; ++f)
        #pragma unroll
        for (int g = 0; g < 4; ++g) acc[f][g] = z;
    const int kbeg = sk * 256;
    #pragma unroll 1
    for (int kt = 0; kt < 4; ++kt) {
        const int kc = kbeg + kt * 64;
        bf16x8 av[4], bv[4];
        #pragma unroll
        for (int i = 0; i < 4; ++i) {
            av[i] = *(const bf16x8*)(A + (size_t)(m0 + srow + 32 * i) * 8192 + kc + scol);
            const float4 w0 = *(const float4*)(Wf + (size_t)(n0 + srow + 32 * i) * 8192 + kc + scol);
            const float4 w1 = *(const float4*)(Wf + (size_t)(n0 + srow + 32 * i) * 8192 + kc + scol + 4);
            bv[i] = pack8(w0, w1);
        }
        __syncthreads();
        #pragma unroll
        for (int i = 0; i < 4; ++i) {
            *(bf16x8*)&As[(srow + 32 * i) * 72 + scol] = av[i];
            *(bf16x8*)&Bs[(srow + 32 * i) * 72 + scol] = bv[i];
        }
        __syncthreads();
        #pragma unroll
        for (int ks = 0; ks < 2; ++ks) {
            bf16x8 af[4], bfr[4];
            #pragma unroll
            for (int f = 0; f < 4; ++f)
                af[f] = *(const bf16x8*)&As[(wm + f * 16 + lr16) * 72 + ks * 32 + lk8];
            #pragma unroll
            for (int g = 0; g < 4; ++g)
                bfr[g] = *(const bf16x8*)&Bs[(wn + g * 16 + lr16) * 72 + ks * 32 + lk8];
            #pragma unroll
            for (int f = 0; f < 4; ++f)
                #pragma unroll
                for (int g = 0; g < 4; ++g)
                    acc[f][g] = __builtin_amdgcn_mfma_f32_16x16x32_bf16(af[f], bfr[g], acc[f][g], 0, 0, 0);
        }
    }
    const int orow = (l >> 4) * 4, ocol = l & 15;
    #pragma unroll
    for (int f = 0; f < 4; ++f) {
        #pragma unroll
        for (int g = 0; g < 4; ++g) {
            #pragma unroll
            for (int j = 0; j < 4; ++j) {
                const int m = m0 + wm + f * 16 + orow + j;
                const int nn = n0 + wn + g * 16 + ocol;
                Cp[((size_t)sk * 256 + m) * 1024 + nn] = f2bf(acc[f][g][j]);
            }
        }
    }
}

// ---------------- K6: fused split-K reduce + bias + lrelu + FC2 ------------------
__global__ __launch_bounds__(256) void k6_fc2(const unsigned short* __restrict__ Cp,
                                              const float* __restrict__ bias,
                                              const float* __restrict__ w,
                                              const float* __restrict__ b,
                                              float* __restrict__ out) {
    const int n = blockIdx.x, t = threadIdx.x;
    const int nn0 = t * 4;
    float s0 = 0.f, s1 = 0.f, s2 = 0.f, s3 = 0.f;
    #pragma unroll
    for (int sk = 0; sk < 32; ++sk) {
        const uint2 u = *(const uint2*)(Cp + ((size_t)sk * 256 + n) * 1024 + nn0);
        s0 += bflo(u.x); s1 += bfhi(u.x); s2 += bflo(u.y); s3 += bfhi(u.y);
    }
    const float4 bi = *(const float4*)(bias + nn0);
    const float4 wv = *(const float4*)(w + nn0);
    float part = lrelu(s0 + bi.x) * wv.x + lrelu(s1 + bi.y) * wv.y +
                 lrelu(s2 + bi.z) * wv.z + lrelu(s3 + bi.w) * wv.w;
    const float2 red = block_reduce_sum2(part, 0.f);
    if (t == 0) out[n] = red.x + b[0];
}

extern "C" void kernel_launch(void* const* d_in, const int* in_sizes, int n_in,
                              void* d_out, int out_size, void* d_ws, size_t ws_size,
                              hipStream_t stream) {
    (void)in_sizes; (void)n_in; (void)out_size; (void)ws_size;
    const float* x    = (const float*)d_in[0];
    // labels (d_in[1]) and conv biases (d_in[3,5,7,9]) cancel exactly under InstanceNorm
    const float* w1   = (const float*)d_in[2];
    const float* w2   = (const float*)d_in[4];
    const float* w3   = (const float*)d_in[6];
    const float* w4   = (const float*)d_in[8];
    const float* fcw1 = (const float*)d_in[10];
    const float* fcb1 = (const float*)d_in[11];
    const float* fcw2 = (const float*)d_in[12];
    const float* fcb2 = (const float*)d_in[13];
    float* out = (float*)d_out;
    float* bufA = (float*)d_ws;                    // 16.7M floats
    float* bufB = bufA + 16777216;                 //  8.4M floats
    unsigned short* h4 = (unsigned short*)bufB;    // standard, 2.1M shorts
    unsigned short* wk = (unsigned short*)bufB + 12582912;  // 43008 shorts, clear of h4
    unsigned short* Cp = (unsigned short*)bufA;    // 32*256*1024 bf16 = 16.8 MB
    wprep<<<42, 1024, 0, stream>>>(w2, w3, w4, wk);
    k1234<<<256, 1024, 0, stream>>>(x, w1, wk, h4);
    k5_fc1<<<512, 256, 0, stream>>>(h4, fcw1, Cp);
    k6_fc2<<<256, 256, 0, stream>>>(Cp, fcb1, fcw2, fcb2, out);
}

// Round 18
// 80.765 us; speedup vs baseline: 1.0768x; 1.0768x over previous
//
#include <hip/hip_runtime.h>

#define EPSI 1e-5f

typedef __attribute__((ext_vector_type(8))) short bf16x8;
typedef __attribute__((ext_vector_type(4))) float f32x4;

__device__ __forceinline__ float lrelu(float x) { return x > 0.f ? x : 0.01f * x; }

// float -> bf16 bits, round-to-nearest-even (header-free)
__device__ __forceinline__ unsigned short f2bf(float x) {
    unsigned int u = __float_as_uint(x);
    return (unsigned short)((u + 0x7fffu + ((u >> 16) & 1u)) >> 16);
}
__device__ __forceinline__ float bflo(unsigned int v) { return __uint_as_float(v << 16); }
__device__ __forceinline__ float bfhi(unsigned int v) { return __uint_as_float(v & 0xFFFF0000u); }
__device__ __forceinline__ unsigned int pack2(float a, float b) {
    return (unsigned int)f2bf(a) | ((unsigned int)f2bf(b) << 16);
}
__device__ __forceinline__ bf16x8 pack8(float4 a, float4 b) {
    union { unsigned short u[8]; bf16x8 v; } p;
    p.u[0] = f2bf(a.x); p.u[1] = f2bf(a.y); p.u[2] = f2bf(a.z); p.u[3] = f2bf(a.w);
    p.u[4] = f2bf(b.x); p.u[5] = f2bf(b.y); p.u[6] = f2bf(b.z); p.u[7] = f2bf(b.w);
    return p.v;
}

// Block-wide sum of (a,b). blockDim.x == 256.
__device__ __forceinline__ float2 block_reduce_sum2(float a, float b) {
    #pragma unroll
    for (int off = 1; off < 64; off <<= 1) {
        a += __shfl_xor(a, off, 64);
        b += __shfl_xor(b, off, 64);
    }
    __shared__ float lds[8];
    const int t = threadIdx.x;
    if ((t & 63) == 0) { lds[2 * (t >> 6)] = a; lds[2 * (t >> 6) + 1] = b; }
    __syncthreads();
    a = lds[0] + lds[2] + lds[4] + lds[6];
    b = lds[1] + lds[3] + lds[5] + lds[7];
    return make_float2(a, b);
}

// Packed activation layouts (bf16), all in LDS inside k1234:
//   h1s [4icq][64y][64x][4c] = 128KB;  h2s [8icq][32y][32x][4c] = 64KB (aliases h1s);
//   h3s [16icq][16y][16x][4c] = 32KB;  ps = 32KB (aliases h2s in phase C).
// h4 global standard [n][128co][64px] (feeds FC1 GEMM).
// Conv GEMM k-order: k = icq*16 + row*8 + tx*4 + c  -> one 16B load per lane K-octet.
// wk: wk2 at 0 (32x64), wk3 at 2048 (64x128), wk4 at 10240 (128x256).

// ---------------- WPREP: reorder conv weights to bf16 wk[co][k] ------------------
__global__ __launch_bounds__(1024) void wprep(const float* __restrict__ w2,
                                              const float* __restrict__ w3,
                                              const float* __restrict__ w4,
                                              unsigned short* __restrict__ wk) {
    const int g = blockIdx.x * 1024 + threadIdx.x;
    if (g < 2048) {
        const int co = g >> 6, k = g & 63;
        const int ic = (k >> 4) * 4 + (k & 3), row = (k >> 3) & 1, tx = (k >> 2) & 1;
        wk[g] = f2bf(w2[co * 144 + ic * 4 + row * 2 + tx]);
    } else if (g < 10240) {
        const int e = g - 2048, co = e >> 7, k = e & 127;
        const int ic = (k >> 4) * 4 + (k & 3), row = (k >> 3) & 1, tx = (k >> 2) & 1;
        wk[g] = f2bf(w3[co * 128 + ic * 4 + row * 2 + tx]);
    } else if (g < 43008) {
        const int e = g - 10240, co = e >> 8, k = e & 255;
        const int ic = (k >> 4) * 4 + (k & 3), row = (k >> 3) & 1, tx = (k >> 2) & 1;
        wk[g] = f2bf(w4[co * 256 + ic * 4 + row * 2 + tx]);
    }
}

// ---------------- K1234: conv1..conv4 fully fused, per-sample --------------------
// 1024 thr (16 waves), 1 block/CU. R17 lessons baked in: phase 0 = R16's
// conflict-free load/store pattern (float2 loads, uint2 stores at 8B lane stride)
// but with x hoisted to registers ONCE and two explicit 8-co passes (acc=32 live,
// no compiler loop-distribution, no re-reads). Phase C = R16's 8-wave version.
__global__ __launch_bounds__(1024, 1) void k1234(const float* __restrict__ x,
                                                 const float* __restrict__ w1,
                                                 const unsigned short* __restrict__ wk,
                                                 unsigned short* __restrict__ h4) {
    const int n = blockIdx.x;
    const int t = threadIdx.x;
    const int w = t >> 6, l = t & 63;
    __shared__ __align__(16) unsigned char smem[131072];   // 128KB phase-aliased
    __shared__ float red[16][64][2];                       // 8KB
    __shared__ float msc[64][2];
    unsigned short* h1s = (unsigned short*)smem;           // [0,128K) phase 0 -> A
    unsigned short* h2s = (unsigned short*)smem;           // [0,64K)  phase A -> B
    unsigned short* h3s = (unsigned short*)(smem + 65536); // [64K,96K) phase B -> C
    float* ps = (float*)smem;                              // [0,32K)  phase C partials

    // ======== Phase 0: conv1 + IN + lrelu -> h1s, 2 explicit co-octet passes =====
    {
        const float* xn = x + (size_t)n * 49152;
        // x held in registers across both passes: 24 float2 = 48 VGPR.
        float2 v0[4][3], v1[4][3];
        #pragma unroll
        for (int q = 0; q < 4; ++q) {
            const int idx = t + 1024 * q;
            const int oy = idx >> 6, ox = idx & 63;
            #pragma unroll
            for (int ic = 0; ic < 3; ++ic) {
                const float* p = xn + ic * 16384;
                v0[q][ic] = ((const float2*)(p + (2 * oy) * 128))[ox];
                v1[q][ic] = ((const float2*)(p + (2 * oy + 1) * 128))[ox];
            }
        }
        #pragma unroll
        for (int pass = 0; pass < 2; ++pass) {
            float acc[8][4];
            #pragma unroll
            for (int j = 0; j < 8; ++j)
                #pragma unroll
                for (int q = 0; q < 4; ++q) acc[j][q] = 0.f;
            #pragma unroll
            for (int j = 0; j < 8; ++j) {
                #pragma unroll
                for (int ic = 0; ic < 3; ++ic) {
                    const float4 wv = *(const float4*)(w1 + (pass * 8 + j) * 12 + ic * 4);  // SGPR
                    #pragma unroll
                    for (int q = 0; q < 4; ++q)
                        acc[j][q] += v0[q][ic].x * wv.x + v0[q][ic].y * wv.y +
                                     v1[q][ic].x * wv.z + v1[q][ic].y * wv.w;
                }
            }
            #pragma unroll
            for (int j = 0; j < 8; ++j) {
                float s1 = acc[j][0] + acc[j][1] + acc[j][2] + acc[j][3];
                float s2 = acc[j][0] * acc[j][0] + acc[j][1] * acc[j][1] +
                           acc[j][2] * acc[j][2] + acc[j][3] * acc[j][3];
                #pragma unroll
                for (int off = 1; off < 64; off <<= 1) {
                    s1 += __shfl_xor(s1, off, 64);
                    s2 += __shfl_xor(s2, off, 64);
                }
                if (l == 0) { red[w][j][0] = s1; red[w][j][1] = s2; }
            }
            __syncthreads();
            if (t < 8) {
                float s1 = 0.f, s2 = 0.f;
                #pragma unroll
                for (int ww = 0; ww < 16; ++ww) { s1 += red[ww][t][0]; s2 += red[ww][t][1]; }
                const float mean = s1 * (1.f / 4096.f);
                const float var = s2 * (1.f / 4096.f) - mean * mean;
                msc[t][0] = mean; msc[t][1] = rsqrtf(var + EPSI);
            }
            __syncthreads();
            #pragma unroll
            for (int q = 0; q < 4; ++q) {
                const int px = t + 1024 * q;
                #pragma unroll
                for (int c4 = 0; c4 < 2; ++c4) {
                    const int icq = pass * 2 + c4;
                    const float n0 = lrelu((acc[c4 * 4 + 0][q] - msc[c4 * 4 + 0][0]) * msc[c4 * 4 + 0][1]);
                    const float n1 = lrelu((acc[c4 * 4 + 1][q] - msc[c4 * 4 + 1][0]) * msc[c4 * 4 + 1][1]);
                    const float n2 = lrelu((acc[c4 * 4 + 2][q] - msc[c4 * 4 + 2][0]) * msc[c4 * 4 + 2][1]);
                    const float n3 = lrelu((acc[c4 * 4 + 3][q] - msc[c4 * 4 + 3][0]) * msc[c4 * 4 + 3][1]);
                    uint2 u; u.x = pack2(n0, n1); u.y = pack2(n2, n3);
                    *(uint2*)(&h1s[((size_t)icq * 4096 + px) * 4]) = u;   // 8B stride: conflict-free
                }
            }
            __syncthreads();   // red/msc reuse; after pass 1 this is phase-A readiness
        }
    }

    // ======== Phase A: conv2 [32co x 64K x 1024px], h1s -> h2s ========
    {
        const unsigned short* wk2 = wk;
        bf16x8 af[2][2];
        #pragma unroll
        for (int cf = 0; cf < 2; ++cf)
            #pragma unroll
            for (int ks = 0; ks < 2; ++ks)
                af[cf][ks] = *(const bf16x8*)(wk2 + (cf * 16 + (l & 15)) * 64 + ks * 32 + (l >> 4) * 8);
        f32x4 acc[4][2];
        const f32x4 z = {0.f, 0.f, 0.f, 0.f};
        #pragma unroll
        for (int pg = 0; pg < 4; ++pg) { acc[pg][0] = z; acc[pg][1] = z; }
        const int row = (l >> 4) & 1, icq0 = (l >> 4) >> 1;
        #pragma unroll
        for (int pg = 0; pg < 4; ++pg) {
            const int oy = 2 * w + (pg >> 1);
            const int ox = (pg & 1) * 16 + (l & 15);
            #pragma unroll
            for (int ks = 0; ks < 2; ++ks) {
                const bf16x8 bv = *(const bf16x8*)(&h1s[(ks * 2 + icq0) * 16384 + (2 * oy + row) * 256 + ox * 8]);
                acc[pg][0] = __builtin_amdgcn_mfma_f32_16x16x32_bf16(af[0][ks], bv, acc[pg][0], 0, 0, 0);
                acc[pg][1] = __builtin_amdgcn_mfma_f32_16x16x32_bf16(af[1][ks], bv, acc[pg][1], 0, 0, 0);
            }
        }
        #pragma unroll
        for (int cf = 0; cf < 2; ++cf) {
            #pragma unroll
            for (int r = 0; r < 4; ++r) {
                float s1 = acc[0][cf][r] + acc[1][cf][r] + acc[2][cf][r] + acc[3][cf][r];
                float s2 = acc[0][cf][r] * acc[0][cf][r] + acc[1][cf][r] * acc[1][cf][r] +
                           acc[2][cf][r] * acc[2][cf][r] + acc[3][cf][r] * acc[3][cf][r];
                #pragma unroll
                for (int off = 1; off < 16; off <<= 1) {
                    s1 += __shfl_xor(s1, off, 64);
                    s2 += __shfl_xor(s2, off, 64);
                }
                if ((l & 15) == 0) {
                    red[w][cf * 16 + (l >> 4) * 4 + r][0] = s1;
                    red[w][cf * 16 + (l >> 4) * 4 + r][1] = s2;
                }
            }
        }
        __syncthreads();   // all h1s reads complete -> h2s may alias h1s
        if (t < 32) {
            float s1 = 0.f, s2 = 0.f;
            #pragma unroll
            for (int ww = 0; ww < 16; ++ww) { s1 += red[ww][t][0]; s2 += red[ww][t][1]; }
            const float mean = s1 * (1.f / 1024.f);
            const float var = s2 * (1.f / 1024.f) - mean * mean;
            msc[t][0] = mean; msc[t][1] = rsqrtf(var + EPSI);
        }
        __syncthreads();
        #pragma unroll
        for (int pg = 0; pg < 4; ++pg) {
            const int px = w * 64 + pg * 16 + (l & 15);
            #pragma unroll
            for (int cf = 0; cf < 2; ++cf) {
                const int co0 = cf * 16 + (l >> 4) * 4;
                float v[4];
                #pragma unroll
                for (int r = 0; r < 4; ++r)
                    v[r] = lrelu((acc[pg][cf][r] - msc[co0 + r][0]) * msc[co0 + r][1]);
                uint2 u; u.x = pack2(v[0], v[1]); u.y = pack2(v[2], v[3]);
                *(uint2*)(&h2s[((cf * 4 + (l >> 4)) * 1024 + px) * 4]) = u;
            }
        }
    }
    __syncthreads();

    // ======== Phase B: conv3 [64co x 128K x 256px], h2s -> h3s ========
    {
        const unsigned short* wk3 = wk + 2048;
        f32x4 acc[4];
        const f32x4 z = {0.f, 0.f, 0.f, 0.f};
        #pragma unroll
        for (int cf = 0; cf < 4; ++cf) acc[cf] = z;
        const int row = (l >> 4) & 1, icq0 = (l >> 4) >> 1;
        #pragma unroll
        for (int ks = 0; ks < 4; ++ks) {
            const bf16x8 bv = *(const bf16x8*)(&h2s[(ks * 2 + icq0) * 4096 + (2 * w + row) * 128 + (l & 15) * 8]);
            #pragma unroll
            for (int cf = 0; cf < 4; ++cf) {
                const bf16x8 af = *(const bf16x8*)(wk3 + (cf * 16 + (l & 15)) * 128 + ks * 32 + (l >> 4) * 8);
                acc[cf] = __builtin_amdgcn_mfma_f32_16x16x32_bf16(af, bv, acc[cf], 0, 0, 0);
            }
        }
        #pragma unroll
        for (int cf = 0; cf < 4; ++cf) {
            #pragma unroll
            for (int r = 0; r < 4; ++r) {
                float s1 = acc[cf][r], s2 = acc[cf][r] * acc[cf][r];
                #pragma unroll
                for (int off = 1; off < 16; off <<= 1) {
                    s1 += __shfl_xor(s1, off, 64);
                    s2 += __shfl_xor(s2, off, 64);
                }
                if ((l & 15) == 0) {
                    red[w][cf * 16 + (l >> 4) * 4 + r][0] = s1;
                    red[w][cf * 16 + (l >> 4) * 4 + r][1] = s2;
                }
            }
        }
        __syncthreads();
        if (t < 64) {
            float s1 = 0.f, s2 = 0.f;
            #pragma unroll
            for (int ww = 0; ww < 16; ++ww) { s1 += red[ww][t][0]; s2 += red[ww][t][1]; }
            const float mean = s1 * (1.f / 256.f);
            const float var = s2 * (1.f / 256.f) - mean * mean;
            msc[t][0] = mean; msc[t][1] = rsqrtf(var + EPSI);
        }
        __syncthreads();
        const int px = w * 16 + (l & 15);
        #pragma unroll
        for (int cf = 0; cf < 4; ++cf) {
            const int co0 = cf * 16 + (l >> 4) * 4;
            float v[4];
            #pragma unroll
            for (int r = 0; r < 4; ++r)
                v[r] = lrelu((acc[cf][r] - msc[co0 + r][0]) * msc[co0 + r][1]);
            uint2 u; u.x = pack2(v[0], v[1]); u.y = pack2(v[2], v[3]);
            *(uint2*)(&h3s[((cf * 4 + (l >> 4)) * 256 + px) * 4]) = u;
        }
    }
    __syncthreads();

    // ======== Phase C: conv4 [128co x 256K x 64px], h3s -> h4 (waves 0-7) ========
    {
        const unsigned short* wk4 = wk + 10240;
        const int cfp = w & 3, khalf = (w >> 2) & 1;
        f32x4 acc[4][2];
        const f32x4 z = {0.f, 0.f, 0.f, 0.f};
        #pragma unroll
        for (int pg = 0; pg < 4; ++pg) { acc[pg][0] = z; acc[pg][1] = z; }
        const int row = (l >> 4) & 1, icq0 = (l >> 4) >> 1;
        const int oyb = (l & 15) >> 3, ox = l & 7;
        if (w < 8) {
            #pragma unroll
            for (int ksl = 0; ksl < 4; ++ksl) {
                const int ks = khalf * 4 + ksl;
                bf16x8 af0 = *(const bf16x8*)(wk4 + ((cfp * 2 + 0) * 16 + (l & 15)) * 256 + ks * 32 + (l >> 4) * 8);
                bf16x8 af1 = *(const bf16x8*)(wk4 + ((cfp * 2 + 1) * 16 + (l & 15)) * 256 + ks * 32 + (l >> 4) * 8);
                #pragma unroll
                for (int pg = 0; pg < 4; ++pg) {
                    const int oy = pg * 2 + oyb;
                    const bf16x8 bv = *(const bf16x8*)(&h3s[(ks * 2 + icq0) * 1024 + (2 * oy + row) * 64 + ox * 8]);
                    acc[pg][0] = __builtin_amdgcn_mfma_f32_16x16x32_bf16(af0, bv, acc[pg][0], 0, 0, 0);
                    acc[pg][1] = __builtin_amdgcn_mfma_f32_16x16x32_bf16(af1, bv, acc[pg][1], 0, 0, 0);
                }
            }
        }
        if (w < 4) {   // khalf == 0: stash partials (ps aliases dead h2s region)
            #pragma unroll
            for (int pg = 0; pg < 4; ++pg)
                #pragma unroll
                for (int cfi = 0; cfi < 2; ++cfi)
                    #pragma unroll
                    for (int r = 0; r < 4; ++r)
                        ps[(cfp * 64 + l) * 32 + pg * 8 + cfi * 4 + r] = acc[pg][cfi][r];
        }
        __syncthreads();
        if (w >= 4 && w < 8) {   // khalf == 1: combine + IN + store
            unsigned short* on = h4 + (size_t)n * 8192;
            #pragma unroll
            for (int cfi = 0; cfi < 2; ++cfi) {
                #pragma unroll
                for (int r = 0; r < 4; ++r) {
                    float v[4];
                    #pragma unroll
                    for (int pg = 0; pg < 4; ++pg)
                        v[pg] = acc[pg][cfi][r] + ps[(cfp * 64 + l) * 32 + pg * 8 + cfi * 4 + r];
                    float s1 = v[0] + v[1] + v[2] + v[3];
                    float s2 = v[0] * v[0] + v[1] * v[1] + v[2] * v[2] + v[3] * v[3];
                    #pragma unroll
                    for (int off = 1; off < 16; off <<= 1) {
                        s1 += __shfl_xor(s1, off, 64);
                        s2 += __shfl_xor(s2, off, 64);
                    }
                    const float mean = s1 * (1.f / 64.f);
                    const float var = s2 * (1.f / 64.f) - mean * mean;
                    const float sc = rsqrtf(var + EPSI);
                    const int co = (cfp * 2 + cfi) * 16 + (l >> 4) * 4 + r;
                    #pragma unroll
                    for (int pg = 0; pg < 4; ++pg)
                        on[co * 64 + pg * 16 + (l & 15)] = f2bf(lrelu((v[pg] - mean) * sc));
                }
            }
        }
    }
}

// ---------------- K5: FC1 bf16 MFMA split-K GEMM, SK=32, bf16 partials -----------
__global__ __launch_bounds__(256, 2) void k5_fc1(const unsigned short* __restrict__ A,
                                                 const float* __restrict__ Wf,
                                                 unsigned short* __restrict__ Cp) {
    __shared__ unsigned short As[128 * 72];
    __shared__ unsigned short Bs[128 * 72];
    const int t = threadIdx.x;
    const int sk = blockIdx.x >> 4;          // 0..31
    const int tile = blockIdx.x & 15;
    const int mt = tile >> 3, nt = tile & 7;
    const int m0 = mt * 128, n0 = nt * 128;
    const int w = t >> 6, l = t & 63;
    const int wm = (w >> 1) * 64, wn = (w & 1) * 64;
    const int lr16 = l & 15, lk8 = (l >> 4) * 8;
    const int srow = t >> 3, scol = (t & 7) * 8;
    f32x4 acc[4][4];
    const f32x4 z = {0.f, 0.f, 0.f, 0.f};
    #pragma unroll
    for (int f = 0; f < 4; ++f)
        #pragma unroll
        for (int g = 0; g < 4; ++g) acc[f][g] = z;
    const int kbeg = sk * 256;
    #pragma unroll 1
    for (int kt = 0; kt < 4; ++kt) {
        const int kc = kbeg + kt * 64;
        bf16x8 av[4], bv[4];
        #pragma unroll
        for (int i = 0; i < 4; ++i) {
            av[i] = *(const bf16x8*)(A + (size_t)(m0 + srow + 32 * i) * 8192 + kc + scol);
            const float4 w0 = *(const float4*)(Wf + (size_t)(n0 + srow + 32 * i) * 8192 + kc + scol);
            const float4 w1 = *(const float4*)(Wf + (size_t)(n0 + srow + 32 * i) * 8192 + kc + scol + 4);
            bv[i] = pack8(w0, w1);
        }
        __syncthreads();
        #pragma unroll
        for (int i = 0; i < 4; ++i) {
            *(bf16x8*)&As[(srow + 32 * i) * 72 + scol] = av[i];
            *(bf16x8*)&Bs[(srow + 32 * i) * 72 + scol] = bv[i];
        }
        __syncthreads();
        #pragma unroll
        for (int ks = 0; ks < 2; ++ks) {
            bf16x8 af[4], bfr[4];
            #pragma unroll
            for (int f = 0; f < 4; ++f)
                af[f] = *(const bf16x8*)&As[(wm + f * 16 + lr16) * 72 + ks * 32 + lk8];
            #pragma unroll
            for (int g = 0; g < 4; ++g)
                bfr[g] = *(const bf16x8*)&Bs[(wn + g * 16 + lr16) * 72 + ks * 32 + lk8];
            #pragma unroll
            for (int f = 0; f < 4; ++f)
                #pragma unroll
                for (int g = 0; g < 4; ++g)
                    acc[f][g] = __builtin_amdgcn_mfma_f32_16x16x32_bf16(af[f], bfr[g], acc[f][g], 0, 0, 0);
        }
    }
    const int orow = (l >> 4) * 4, ocol = l & 15;
    #pragma unroll
    for (int f = 0; f < 4; ++f) {
        #pragma unroll
        for (int g = 0; g < 4; ++g) {
            #pragma unroll
            for (int j = 0; j < 4; ++j) {
                const int m = m0 + wm + f * 16 + orow + j;
                const int nn = n0 + wn + g * 16 + ocol;
                Cp[((size_t)sk * 256 + m) * 1024 + nn] = f2bf(acc[f][g][j]);
            }
        }
    }
}

// ---------------- K6: fused split-K reduce + bias + lrelu + FC2 ------------------
__global__ __launch_bounds__(256) void k6_fc2(const unsigned short* __restrict__ Cp,
                                              const float* __restrict__ bias,
                                              const float* __restrict__ w,
                                              const float* __restrict__ b,
                                              float* __restrict__ out) {
    const int n = blockIdx.x, t = threadIdx.x;
    const int nn0 = t * 4;
    float s0 = 0.f, s1 = 0.f, s2 = 0.f, s3 = 0.f;
    #pragma unroll
    for (int sk = 0; sk < 32; ++sk) {
        const uint2 u = *(const uint2*)(Cp + ((size_t)sk * 256 + n) * 1024 + nn0);
        s0 += bflo(u.x); s1 += bfhi(u.x); s2 += bflo(u.y); s3 += bfhi(u.y);
    }
    const float4 bi = *(const float4*)(bias + nn0);
    const float4 wv = *(const float4*)(w + nn0);
    float part = lrelu(s0 + bi.x) * wv.x + lrelu(s1 + bi.y) * wv.y +
                 lrelu(s2 + bi.z) * wv.z + lrelu(s3 + bi.w) * wv.w;
    const float2 red = block_reduce_sum2(part, 0.f);
    if (t == 0) out[n] = red.x + b[0];
}

extern "C" void kernel_launch(void* const* d_in, const int* in_sizes, int n_in,
                              void* d_out, int out_size, void* d_ws, size_t ws_size,
                              hipStream_t stream) {
    (void)in_sizes; (void)n_in; (void)out_size; (void)ws_size;
    const float* x    = (const float*)d_in[0];
    // labels (d_in[1]) and conv biases (d_in[3,5,7,9]) cancel exactly under InstanceNorm
    const float* w1   = (const float*)d_in[2];
    const float* w2   = (const float*)d_in[4];
    const float* w3   = (const float*)d_in[6];
    const float* w4   = (const float*)d_in[8];
    const float* fcw1 = (const float*)d_in[10];
    const float* fcb1 = (const float*)d_in[11];
    const float* fcw2 = (const float*)d_in[12];
    const float* fcb2 = (const float*)d_in[13];
    float* out = (float*)d_out;
    float* bufA = (float*)d_ws;                    // 16.7M floats
    float* bufB = bufA + 16777216;                 //  8.4M floats
    unsigned short* h4 = (unsigned short*)bufB;    // standard, 2.1M shorts
    unsigned short* wk = (unsigned short*)bufB + 12582912;  // 43008 shorts, clear of h4
    unsigned short* Cp = (unsigned short*)bufA;    // 32*256*1024 bf16 = 16.8 MB
    wprep<<<42, 1024, 0, stream>>>(w2, w3, w4, wk);
    k1234<<<256, 1024, 0, stream>>>(x, w1, wk, h4);
    k5_fc1<<<512, 256, 0, stream>>>(h4, fcw1, Cp);
    k6_fc2<<<256, 256, 0, stream>>>(Cp, fcb1, fcw2, fcb2, out);
}

// Round 19
// 74.786 us; speedup vs baseline: 1.1629x; 1.0799x over previous
//
#include <hip/hip_runtime.h>

#define EPSI 1e-5f

typedef __attribute__((ext_vector_type(8))) short bf16x8;
typedef __attribute__((ext_vector_type(4))) float f32x4;

__device__ __forceinline__ float lrelu(float x) { return x > 0.f ? x : 0.01f * x; }

// float -> bf16 bits, round-to-nearest-even (header-free)
__device__ __forceinline__ unsigned short f2bf(float x) {
    unsigned int u = __float_as_uint(x);
    return (unsigned short)((u + 0x7fffu + ((u >> 16) & 1u)) >> 16);
}
__device__ __forceinline__ float bflo(unsigned int v) { return __uint_as_float(v << 16); }
__device__ __forceinline__ float bfhi(unsigned int v) { return __uint_as_float(v & 0xFFFF0000u); }
__device__ __forceinline__ unsigned int pack2(float a, float b) {
    return (unsigned int)f2bf(a) | ((unsigned int)f2bf(b) << 16);
}
__device__ __forceinline__ bf16x8 pack8(float4 a, float4 b) {
    union { unsigned short u[8]; bf16x8 v; } p;
    p.u[0] = f2bf(a.x); p.u[1] = f2bf(a.y); p.u[2] = f2bf(a.z); p.u[3] = f2bf(a.w);
    p.u[4] = f2bf(b.x); p.u[5] = f2bf(b.y); p.u[6] = f2bf(b.z); p.u[7] = f2bf(b.w);
    return p.v;
}

// Block-wide sum of (a,b). blockDim.x == 256.
__device__ __forceinline__ float2 block_reduce_sum2(float a, float b) {
    #pragma unroll
    for (int off = 1; off < 64; off <<= 1) {
        a += __shfl_xor(a, off, 64);
        b += __shfl_xor(b, off, 64);
    }
    __shared__ float lds[8];
    const int t = threadIdx.x;
    if ((t & 63) == 0) { lds[2 * (t >> 6)] = a; lds[2 * (t >> 6) + 1] = b; }
    __syncthreads();
    a = lds[0] + lds[2] + lds[4] + lds[6];
    b = lds[1] + lds[3] + lds[5] + lds[7];
    return make_float2(a, b);
}

// Packed activation layouts (bf16), all in LDS inside k1234:
//   h1s [4icq][64y][64x][4c] = 128KB;  h2s [8icq][32y][32x][4c] = 64KB (aliases h1s);
//   h3s [16icq][16y][16x][4c] = 32KB;  ps = 32KB (aliases h2s in phase C).
// h4 global standard [n][128co][64px] (feeds FC1 GEMM).
// Conv GEMM k-order: k = icq*16 + row*8 + tx*4 + c  -> one 16B load per lane K-octet.
// wk: wk2 at 0 (32x64), wk3 at 2048 (64x128), wk4 at 10240 (128x256).

// ---------------- WPREP: reorder conv weights to bf16 wk[co][k] ------------------
__global__ __launch_bounds__(1024) void wprep(const float* __restrict__ w2,
                                              const float* __restrict__ w3,
                                              const float* __restrict__ w4,
                                              unsigned short* __restrict__ wk) {
    const int g = blockIdx.x * 1024 + threadIdx.x;
    if (g < 2048) {
        const int co = g >> 6, k = g & 63;
        const int ic = (k >> 4) * 4 + (k & 3), row = (k >> 3) & 1, tx = (k >> 2) & 1;
        wk[g] = f2bf(w2[co * 144 + ic * 4 + row * 2 + tx]);
    } else if (g < 10240) {
        const int e = g - 2048, co = e >> 7, k = e & 127;
        const int ic = (k >> 4) * 4 + (k & 3), row = (k >> 3) & 1, tx = (k >> 2) & 1;
        wk[g] = f2bf(w3[co * 128 + ic * 4 + row * 2 + tx]);
    } else if (g < 43008) {
        const int e = g - 10240, co = e >> 8, k = e & 255;
        const int ic = (k >> 4) * 4 + (k & 3), row = (k >> 3) & 1, tx = (k >> 2) & 1;
        wk[g] = f2bf(w4[co * 256 + ic * 4 + row * 2 + tx]);
    }
}

// ---------------- K1234: conv1+conv2+conv3+conv4 fully fused, per-sample ---------
// 1024 thr (16 waves), 1 block/CU. h1 never touches HBM. R16 configuration
// verbatim (best measured): R17/R18 experiments on phase-0 scheduling and
// phase-C wave count both regressed — the compiler's own phase-0 schedule wins.
__global__ __launch_bounds__(1024, 1) void k1234(const float* __restrict__ x,
                                                 const float* __restrict__ w1,
                                                 const unsigned short* __restrict__ wk,
                                                 unsigned short* __restrict__ h4) {
    const int n = blockIdx.x;
    const int t = threadIdx.x;
    const int w = t >> 6, l = t & 63;
    __shared__ __align__(16) unsigned char smem[131072];   // 128KB phase-aliased
    __shared__ float red[16][64][2];                       // 8KB
    __shared__ float msc[64][2];
    unsigned short* h1s = (unsigned short*)smem;           // [0,128K) phase 0 -> A
    unsigned short* h2s = (unsigned short*)smem;           // [0,64K)  phase A -> B
    unsigned short* h3s = (unsigned short*)(smem + 65536); // [64K,96K) phase B -> C
    float* ps = (float*)smem;                              // [0,32K)  phase C partials

    // ======== Phase 0: conv1 (VALU) + IN + lrelu -> h1s (LDS) ========
    {
        const float* xn = x + (size_t)n * 49152;
        float acc[16][4];
        #pragma unroll
        for (int j = 0; j < 16; ++j)
            #pragma unroll
            for (int q = 0; q < 4; ++q) acc[j][q] = 0.f;
        #pragma unroll 1
        for (int ic = 0; ic < 3; ++ic) {
            const float* p = xn + ic * 16384;
            float2 v0[4], v1[4];
            #pragma unroll
            for (int q = 0; q < 4; ++q) {
                const int idx = t + 1024 * q;
                const int oy = idx >> 6, ox = idx & 63;
                v0[q] = ((const float2*)(p + (2 * oy) * 128))[ox];
                v1[q] = ((const float2*)(p + (2 * oy + 1) * 128))[ox];
            }
            #pragma unroll
            for (int j = 0; j < 16; ++j) {
                const float4 wv = *(const float4*)(w1 + j * 12 + ic * 4);  // uniform -> SGPR
                #pragma unroll
                for (int q = 0; q < 4; ++q)
                    acc[j][q] += v0[q].x * wv.x + v0[q].y * wv.y + v1[q].x * wv.z + v1[q].y * wv.w;
            }
        }
        #pragma unroll
        for (int j = 0; j < 16; ++j) {
            float s1 = acc[j][0] + acc[j][1] + acc[j][2] + acc[j][3];
            float s2 = acc[j][0] * acc[j][0] + acc[j][1] * acc[j][1] +
                       acc[j][2] * acc[j][2] + acc[j][3] * acc[j][3];
            #pragma unroll
            for (int off = 1; off < 64; off <<= 1) {
                s1 += __shfl_xor(s1, off, 64);
                s2 += __shfl_xor(s2, off, 64);
            }
            if (l == 0) { red[w][j][0] = s1; red[w][j][1] = s2; }
        }
        __syncthreads();
        if (t < 16) {
            float s1 = 0.f, s2 = 0.f;
            #pragma unroll
            for (int ww = 0; ww < 16; ++ww) { s1 += red[ww][t][0]; s2 += red[ww][t][1]; }
            const float mean = s1 * (1.f / 4096.f);
            const float var = s2 * (1.f / 4096.f) - mean * mean;
            msc[t][0] = mean; msc[t][1] = rsqrtf(var + EPSI);
        }
        __syncthreads();
        #pragma unroll
        for (int q = 0; q < 4; ++q) {
            const int px = t + 1024 * q;
            #pragma unroll
            for (int q4 = 0; q4 < 4; ++q4) {
                const float n0 = lrelu((acc[4 * q4 + 0][q] - msc[4 * q4 + 0][0]) * msc[4 * q4 + 0][1]);
                const float n1 = lrelu((acc[4 * q4 + 1][q] - msc[4 * q4 + 1][0]) * msc[4 * q4 + 1][1]);
                const float n2 = lrelu((acc[4 * q4 + 2][q] - msc[4 * q4 + 2][0]) * msc[4 * q4 + 2][1]);
                const float n3 = lrelu((acc[4 * q4 + 3][q] - msc[4 * q4 + 3][0]) * msc[4 * q4 + 3][1]);
                uint2 u; u.x = pack2(n0, n1); u.y = pack2(n2, n3);
                *(uint2*)(&h1s[((size_t)q4 * 4096 + px) * 4]) = u;
            }
        }
    }
    __syncthreads();

    // ======== Phase A: conv2 [32co x 64K x 1024px], h1s -> h2s ========
    {
        const unsigned short* wk2 = wk;
        bf16x8 af[2][2];
        #pragma unroll
        for (int cf = 0; cf < 2; ++cf)
            #pragma unroll
            for (int ks = 0; ks < 2; ++ks)
                af[cf][ks] = *(const bf16x8*)(wk2 + (cf * 16 + (l & 15)) * 64 + ks * 32 + (l >> 4) * 8);
        f32x4 acc[4][2];
        const f32x4 z = {0.f, 0.f, 0.f, 0.f};
        #pragma unroll
        for (int pg = 0; pg < 4; ++pg) { acc[pg][0] = z; acc[pg][1] = z; }
        const int row = (l >> 4) & 1, icq0 = (l >> 4) >> 1;
        #pragma unroll
        for (int pg = 0; pg < 4; ++pg) {
            const int oy = 2 * w + (pg >> 1);
            const int ox = (pg & 1) * 16 + (l & 15);
            #pragma unroll
            for (int ks = 0; ks < 2; ++ks) {
                const bf16x8 bv = *(const bf16x8*)(&h1s[(ks * 2 + icq0) * 16384 + (2 * oy + row) * 256 + ox * 8]);
                acc[pg][0] = __builtin_amdgcn_mfma_f32_16x16x32_bf16(af[0][ks], bv, acc[pg][0], 0, 0, 0);
                acc[pg][1] = __builtin_amdgcn_mfma_f32_16x16x32_bf16(af[1][ks], bv, acc[pg][1], 0, 0, 0);
            }
        }
        #pragma unroll
        for (int cf = 0; cf < 2; ++cf) {
            #pragma unroll
            for (int r = 0; r < 4; ++r) {
                float s1 = acc[0][cf][r] + acc[1][cf][r] + acc[2][cf][r] + acc[3][cf][r];
                float s2 = acc[0][cf][r] * acc[0][cf][r] + acc[1][cf][r] * acc[1][cf][r] +
                           acc[2][cf][r] * acc[2][cf][r] + acc[3][cf][r] * acc[3][cf][r];
                #pragma unroll
                for (int off = 1; off < 16; off <<= 1) {
                    s1 += __shfl_xor(s1, off, 64);
                    s2 += __shfl_xor(s2, off, 64);
                }
                if ((l & 15) == 0) {
                    red[w][cf * 16 + (l >> 4) * 4 + r][0] = s1;
                    red[w][cf * 16 + (l >> 4) * 4 + r][1] = s2;
                }
            }
        }
        __syncthreads();   // all h1s reads complete here -> h2s may alias h1s
        if (t < 32) {
            float s1 = 0.f, s2 = 0.f;
            #pragma unroll
            for (int ww = 0; ww < 16; ++ww) { s1 += red[ww][t][0]; s2 += red[ww][t][1]; }
            const float mean = s1 * (1.f / 1024.f);
            const float var = s2 * (1.f / 1024.f) - mean * mean;
            msc[t][0] = mean; msc[t][1] = rsqrtf(var + EPSI);
        }
        __syncthreads();
        #pragma unroll
        for (int pg = 0; pg < 4; ++pg) {
            const int px = w * 64 + pg * 16 + (l & 15);
            #pragma unroll
            for (int cf = 0; cf < 2; ++cf) {
                const int co0 = cf * 16 + (l >> 4) * 4;
                float v[4];
                #pragma unroll
                for (int r = 0; r < 4; ++r)
                    v[r] = lrelu((acc[pg][cf][r] - msc[co0 + r][0]) * msc[co0 + r][1]);
                uint2 u; u.x = pack2(v[0], v[1]); u.y = pack2(v[2], v[3]);
                *(uint2*)(&h2s[((cf * 4 + (l >> 4)) * 1024 + px) * 4]) = u;
            }
        }
    }
    __syncthreads();

    // ======== Phase B: conv3 [64co x 128K x 256px], h2s -> h3s ========
    {
        const unsigned short* wk3 = wk + 2048;
        f32x4 acc[4];
        const f32x4 z = {0.f, 0.f, 0.f, 0.f};
        #pragma unroll
        for (int cf = 0; cf < 4; ++cf) acc[cf] = z;
        const int row = (l >> 4) & 1, icq0 = (l >> 4) >> 1;
        #pragma unroll
        for (int ks = 0; ks < 4; ++ks) {
            const bf16x8 bv = *(const bf16x8*)(&h2s[(ks * 2 + icq0) * 4096 + (2 * w + row) * 128 + (l & 15) * 8]);
            #pragma unroll
            for (int cf = 0; cf < 4; ++cf) {
                const bf16x8 af = *(const bf16x8*)(wk3 + (cf * 16 + (l & 15)) * 128 + ks * 32 + (l >> 4) * 8);
                acc[cf] = __builtin_amdgcn_mfma_f32_16x16x32_bf16(af, bv, acc[cf], 0, 0, 0);
            }
        }
        #pragma unroll
        for (int cf = 0; cf < 4; ++cf) {
            #pragma unroll
            for (int r = 0; r < 4; ++r) {
                float s1 = acc[cf][r], s2 = acc[cf][r] * acc[cf][r];
                #pragma unroll
                for (int off = 1; off < 16; off <<= 1) {
                    s1 += __shfl_xor(s1, off, 64);
                    s2 += __shfl_xor(s2, off, 64);
                }
                if ((l & 15) == 0) {
                    red[w][cf * 16 + (l >> 4) * 4 + r][0] = s1;
                    red[w][cf * 16 + (l >> 4) * 4 + r][1] = s2;
                }
            }
        }
        __syncthreads();
        if (t < 64) {
            float s1 = 0.f, s2 = 0.f;
            #pragma unroll
            for (int ww = 0; ww < 16; ++ww) { s1 += red[ww][t][0]; s2 += red[ww][t][1]; }
            const float mean = s1 * (1.f / 256.f);
            const float var = s2 * (1.f / 256.f) - mean * mean;
            msc[t][0] = mean; msc[t][1] = rsqrtf(var + EPSI);
        }
        __syncthreads();
        const int px = w * 16 + (l & 15);
        #pragma unroll
        for (int cf = 0; cf < 4; ++cf) {
            const int co0 = cf * 16 + (l >> 4) * 4;
            float v[4];
            #pragma unroll
            for (int r = 0; r < 4; ++r)
                v[r] = lrelu((acc[cf][r] - msc[co0 + r][0]) * msc[co0 + r][1]);
            uint2 u; u.x = pack2(v[0], v[1]); u.y = pack2(v[2], v[3]);
            *(uint2*)(&h3s[((cf * 4 + (l >> 4)) * 256 + px) * 4]) = u;
        }
    }
    __syncthreads();

    // ======== Phase C: conv4 [128co x 256K x 64px], h3s -> h4 (waves 0-7) ========
    {
        const unsigned short* wk4 = wk + 10240;
        const int cfp = w & 3, khalf = (w >> 2) & 1;
        f32x4 acc[4][2];
        const f32x4 z = {0.f, 0.f, 0.f, 0.f};
        #pragma unroll
        for (int pg = 0; pg < 4; ++pg) { acc[pg][0] = z; acc[pg][1] = z; }
        const int row = (l >> 4) & 1, icq0 = (l >> 4) >> 1;
        const int oyb = (l & 15) >> 3, ox = l & 7;
        if (w < 8) {
            #pragma unroll
            for (int ksl = 0; ksl < 4; ++ksl) {
                const int ks = khalf * 4 + ksl;
                bf16x8 af0 = *(const bf16x8*)(wk4 + ((cfp * 2 + 0) * 16 + (l & 15)) * 256 + ks * 32 + (l >> 4) * 8);
                bf16x8 af1 = *(const bf16x8*)(wk4 + ((cfp * 2 + 1) * 16 + (l & 15)) * 256 + ks * 32 + (l >> 4) * 8);
                #pragma unroll
                for (int pg = 0; pg < 4; ++pg) {
                    const int oy = pg * 2 + oyb;
                    const bf16x8 bv = *(const bf16x8*)(&h3s[(ks * 2 + icq0) * 1024 + (2 * oy + row) * 64 + ox * 8]);
                    acc[pg][0] = __builtin_amdgcn_mfma_f32_16x16x32_bf16(af0, bv, acc[pg][0], 0, 0, 0);
                    acc[pg][1] = __builtin_amdgcn_mfma_f32_16x16x32_bf16(af1, bv, acc[pg][1], 0, 0, 0);
                }
            }
        }
        if (w < 4) {   // khalf == 0: stash partials (ps aliases dead h2s region)
            #pragma unroll
            for (int pg = 0; pg < 4; ++pg)
                #pragma unroll
                for (int cfi = 0; cfi < 2; ++cfi)
                    #pragma unroll
                    for (int r = 0; r < 4; ++r)
                        ps[(cfp * 64 + l) * 32 + pg * 8 + cfi * 4 + r] = acc[pg][cfi][r];
        }
        __syncthreads();
        if (w >= 4 && w < 8) {   // khalf == 1: combine + IN + store
            unsigned short* on = h4 + (size_t)n * 8192;
            #pragma unroll
            for (int cfi = 0; cfi < 2; ++cfi) {
                #pragma unroll
                for (int r = 0; r < 4; ++r) {
                    float v[4];
                    #pragma unroll
                    for (int pg = 0; pg < 4; ++pg)
                        v[pg] = acc[pg][cfi][r] + ps[(cfp * 64 + l) * 32 + pg * 8 + cfi * 4 + r];
                    float s1 = v[0] + v[1] + v[2] + v[3];
                    float s2 = v[0] * v[0] + v[1] * v[1] + v[2] * v[2] + v[3] * v[3];
                    #pragma unroll
                    for (int off = 1; off < 16; off <<= 1) {
                        s1 += __shfl_xor(s1, off, 64);
                        s2 += __shfl_xor(s2, off, 64);
                    }
                    const float mean = s1 * (1.f / 64.f);
                    const float var = s2 * (1.f / 64.f) - mean * mean;
                    const float sc = rsqrtf(var + EPSI);
                    const int co = (cfp * 2 + cfi) * 16 + (l >> 4) * 4 + r;
                    #pragma unroll
                    for (int pg = 0; pg < 4; ++pg)
                        on[co * 64 + pg * 16 + (l & 15)] = f2bf(lrelu((v[pg] - mean) * sc));
                }
            }
        }
    }
}

// ---------------- K5: FC1 bf16 MFMA split-K GEMM, SK=32, bf16 partials -----------
// C[256,1024] = A[256,8192](bf16) x W[1024,8192]^T(fp32->bf16 on the fly).
// BM=BN=128, BK=64, SK=32: grid = 512 blocks (2/CU on all 256 CUs).
__global__ __launch_bounds__(256, 2) void k5_fc1(const unsigned short* __restrict__ A,
                                                 const float* __restrict__ Wf,
                                                 unsigned short* __restrict__ Cp) {
    __shared__ unsigned short As[128 * 72];
    __shared__ unsigned short Bs[128 * 72];
    const int t = threadIdx.x;
    const int sk = blockIdx.x >> 4;          // 0..31
    const int tile = blockIdx.x & 15;
    const int mt = tile >> 3, nt = tile & 7;
    const int m0 = mt * 128, n0 = nt * 128;
    const int w = t >> 6, l = t & 63;
    const int wm = (w >> 1) * 64, wn = (w & 1) * 64;
    const int lr16 = l & 15, lk8 = (l >> 4) * 8;
    const int srow = t >> 3, scol = (t & 7) * 8;
    f32x4 acc[4][4];
    const f32x4 z = {0.f, 0.f, 0.f, 0.f};
    #pragma unroll
    for (int f = 0; f < 4; ++f)
        #pragma unroll
        for (int g = 0; g < 4; ++g) acc[f][g] = z;
    const int kbeg = sk * 256;
    #pragma unroll 1
    for (int kt = 0; kt < 4; ++kt) {
        const int kc = kbeg + kt * 64;
        bf16x8 av[4], bv[4];
        #pragma unroll
        for (int i = 0; i < 4; ++i) {
            av[i] = *(const bf16x8*)(A + (size_t)(m0 + srow + 32 * i) * 8192 + kc + scol);
            const float4 w0 = *(const float4*)(Wf + (size_t)(n0 + srow + 32 * i) * 8192 + kc + scol);
            const float4 w1 = *(const float4*)(Wf + (size_t)(n0 + srow + 32 * i) * 8192 + kc + scol + 4);
            bv[i] = pack8(w0, w1);
        }
        __syncthreads();
        #pragma unroll
        for (int i = 0; i < 4; ++i) {
            *(bf16x8*)&As[(srow + 32 * i) * 72 + scol] = av[i];
            *(bf16x8*)&Bs[(srow + 32 * i) * 72 + scol] = bv[i];
        }
        __syncthreads();
        #pragma unroll
        for (int ks = 0; ks < 2; ++ks) {
            bf16x8 af[4], bfr[4];
            #pragma unroll
            for (int f = 0; f < 4; ++f)
                af[f] = *(const bf16x8*)&As[(wm + f * 16 + lr16) * 72 + ks * 32 + lk8];
            #pragma unroll
            for (int g = 0; g < 4; ++g)
                bfr[g] = *(const bf16x8*)&Bs[(wn + g * 16 + lr16) * 72 + ks * 32 + lk8];
            #pragma unroll
            for (int f = 0; f < 4; ++f)
                #pragma unroll
                for (int g = 0; g < 4; ++g)
                    acc[f][g] = __builtin_amdgcn_mfma_f32_16x16x32_bf16(af[f], bfr[g], acc[f][g], 0, 0, 0);
        }
    }
    const int orow = (l >> 4) * 4, ocol = l & 15;
    #pragma unroll
    for (int f = 0; f < 4; ++f) {
        #pragma unroll
        for (int g = 0; g < 4; ++g) {
            #pragma unroll
            for (int j = 0; j < 4; ++j) {
                const int m = m0 + wm + f * 16 + orow + j;
                const int nn = n0 + wn + g * 16 + ocol;
                Cp[((size_t)sk * 256 + m) * 1024 + nn] = f2bf(acc[f][g][j]);
            }
        }
    }
}

// ---------------- K6: fused split-K reduce + bias + lrelu + FC2 ------------------
// Thread t owns nn = 4t..4t+3: one uint2 (4 bf16) load per sk partial.
__global__ __launch_bounds__(256) void k6_fc2(const unsigned short* __restrict__ Cp,
                                              const float* __restrict__ bias,
                                              const float* __restrict__ w,
                                              const float* __restrict__ b,
                                              float* __restrict__ out) {
    const int n = blockIdx.x, t = threadIdx.x;
    const int nn0 = t * 4;
    float s0 = 0.f, s1 = 0.f, s2 = 0.f, s3 = 0.f;
    #pragma unroll
    for (int sk = 0; sk < 32; ++sk) {
        const uint2 u = *(const uint2*)(Cp + ((size_t)sk * 256 + n) * 1024 + nn0);
        s0 += bflo(u.x); s1 += bfhi(u.x); s2 += bflo(u.y); s3 += bfhi(u.y);
    }
    const float4 bi = *(const float4*)(bias + nn0);
    const float4 wv = *(const float4*)(w + nn0);
    float part = lrelu(s0 + bi.x) * wv.x + lrelu(s1 + bi.y) * wv.y +
                 lrelu(s2 + bi.z) * wv.z + lrelu(s3 + bi.w) * wv.w;
    const float2 red = block_reduce_sum2(part, 0.f);
    if (t == 0) out[n] = red.x + b[0];
}

extern "C" void kernel_launch(void* const* d_in, const int* in_sizes, int n_in,
                              void* d_out, int out_size, void* d_ws, size_t ws_size,
                              hipStream_t stream) {
    (void)in_sizes; (void)n_in; (void)out_size; (void)ws_size;
    const float* x    = (const float*)d_in[0];
    // labels (d_in[1]) and conv biases (d_in[3,5,7,9]) cancel exactly under InstanceNorm
    const float* w1   = (const float*)d_in[2];
    const float* w2   = (const float*)d_in[4];
    const float* w3   = (const float*)d_in[6];
    const float* w4   = (const float*)d_in[8];
    const float* fcw1 = (const float*)d_in[10];
    const float* fcb1 = (const float*)d_in[11];
    const float* fcw2 = (const float*)d_in[12];
    const float* fcb2 = (const float*)d_in[13];
    float* out = (float*)d_out;
    float* bufA = (float*)d_ws;                    // 16.7M floats
    float* bufB = bufA + 16777216;                 //  8.4M floats
    unsigned short* h4 = (unsigned short*)bufB;    // standard, 2.1M shorts
    unsigned short* wk = (unsigned short*)bufB + 12582912;  // 43008 shorts, clear of h4
    unsigned short* Cp = (unsigned short*)bufA;    // 32*256*1024 bf16 = 16.8 MB
    wprep<<<42, 1024, 0, stream>>>(w2, w3, w4, wk);
    k1234<<<256, 1024, 0, stream>>>(x, w1, wk, h4);
    k5_fc1<<<512, 256, 0, stream>>>(h4, fcw1, Cp);
    k6_fc2<<<256, 256, 0, stream>>>(Cp, fcb1, fcw2, fcb2, out);
}